// Round 4
// baseline (262.137 us; speedup 1.0000x reference)
//
#include <hip/hip_runtime.h>

#define DCH 512     // channels
#define RPB 32      // rows per block (63488 % 32 == 0 -> no tail)
#define HALO 6
#define NW  (RPB + HALO)   // 38 window rows: r0-3 .. r0+RPB+2
#define PFD 6              // prefetch depth beyond the 7-row window

typedef float f32x4 __attribute__((ext_vector_type(4)));

// Counted wait + scheduling fence (rule 18). Switch folds to one literal
// under full unroll (n is compile-time constant per unrolled iteration).
__device__ __forceinline__ void vmwait_sb(int n) {
    switch (n) {
        case 0:  asm volatile("s_waitcnt vmcnt(0)"  ::: "memory"); break;
        case 1:  asm volatile("s_waitcnt vmcnt(1)"  ::: "memory"); break;
        case 2:  asm volatile("s_waitcnt vmcnt(2)"  ::: "memory"); break;
        case 3:  asm volatile("s_waitcnt vmcnt(3)"  ::: "memory"); break;
        case 4:  asm volatile("s_waitcnt vmcnt(4)"  ::: "memory"); break;
        case 5:  asm volatile("s_waitcnt vmcnt(5)"  ::: "memory"); break;
        case 6:  asm volatile("s_waitcnt vmcnt(6)"  ::: "memory"); break;
        case 7:  asm volatile("s_waitcnt vmcnt(7)"  ::: "memory"); break;
        case 8:  asm volatile("s_waitcnt vmcnt(8)"  ::: "memory"); break;
        case 9:  asm volatile("s_waitcnt vmcnt(9)"  ::: "memory"); break;
        case 10: asm volatile("s_waitcnt vmcnt(10)" ::: "memory"); break;
        case 11: asm volatile("s_waitcnt vmcnt(11)" ::: "memory"); break;
        case 12: asm volatile("s_waitcnt vmcnt(12)" ::: "memory"); break;
        case 13: asm volatile("s_waitcnt vmcnt(13)" ::: "memory"); break;
        case 14: asm volatile("s_waitcnt vmcnt(14)" ::: "memory"); break;
        default: asm volatile("s_waitcnt vmcnt(0)"  ::: "memory"); break; // safe fallback
    }
    __builtin_amdgcn_sched_barrier(0);
}

__global__ __launch_bounds__(128) void ppeg_dwconv_kernel(
    const float* __restrict__ x,
    const float* __restrict__ w3, const float* __restrict__ b3,
    const float* __restrict__ w5, const float* __restrict__ b5,
    const float* __restrict__ w7, const float* __restrict__ b7,
    const int* __restrict__ lengths,
    float* __restrict__ out, int n_rows, int n_bags, int nblocks)
{
    __shared__ int soff[40];   // prefix offsets, n_bags+1 entries

    const int tid = threadIdx.x;
    const int c0  = tid * 4;           // this thread's 4 channels

    // XCD-aware bijective swizzle: consecutive tiles share an XCD's L2
    // (R1 evidence: FETCH_SIZE 87.6 -> 65.8 MB).
    int bid = blockIdx.x;
    {
        const int nx = 8;
        const int q  = nblocks / nx, rm = nblocks % nx;
        const int xcd = bid % nx, idx = bid / nx;
        bid = (xcd < rm ? xcd * (q + 1) : rm * (q + 1) + (xcd - rm) * q) + idx;
    }
    const int r0 = bid * RPB;
    if (r0 >= n_rows) return;

    if (tid == 0) {
        int acc = 0;
        for (int i = 0; i < n_bags; ++i) { soff[i] = acc; acc += lengths[i]; }
        soff[n_bags] = acc;
    }

    // Weights first: these compiler-visible vmem loads are fully consumed
    // (and waited) before the asm burst, so no compiler wait can interfere
    // with the hand-counted pipeline below.
    float W[7][4], bias[4];
    #pragma unroll
    for (int q2 = 0; q2 < 4; ++q2) {
        const int d = c0 + q2;
        const float a0 = w7[d*7+0], a1 = w7[d*7+1], a2 = w7[d*7+2], a3 = w7[d*7+3],
                    a4 = w7[d*7+4], a5 = w7[d*7+5], a6 = w7[d*7+6];
        const float f0 = w5[d*5+0], f1 = w5[d*5+1], f2 = w5[d*5+2], f3 = w5[d*5+3], f4 = w5[d*5+4];
        const float e0 = w3[d*3+0], e1 = w3[d*3+1], e2 = w3[d*3+2];
        W[0][q2] = a0;
        W[1][q2] = a1 + f0;
        W[2][q2] = a2 + f1 + e0;
        W[3][q2] = a3 + f2 + e1 + 1.0f;
        W[4][q2] = a4 + f3 + e2;
        W[5][q2] = a5 + f4;
        W[6][q2] = a6;
        bias[q2] = b3[d] + b5[d] + b7[d];
    }

    __syncthreads();

    // Binary search for bag containing r0 (uniform, 5 LDS reads).
    int b = 0;
    #pragma unroll
    for (int s = 16; s >= 1; s >>= 1)
        if (b + s < n_bags && soff[b + s] <= r0) b += s;

    // A 32-row tile crosses at most one bag boundary (min bag = 2049 rows).
    const int e0b = soff[b];
    const int e1b = soff[b + 1];
    const int e2b = (b + 2 <= n_bags) ? soff[b + 2] : e1b;

    const bool interior = (r0 >= 3) && (r0 + RPB + 2 < n_rows);

    if (interior) {
        const float* xbase = x + (size_t)(r0 - 3) * DCH + c0;
        float*       obase = out + (size_t)r0 * DCH + c0;

        // Rotating pipeline: window liveness stays at 14 float4 (56 VGPR)
        // because each load is issued only PFD+1 rows ahead of its use —
        // spill-free by construction (R2/R3 post-mortem: 22-up-front spilled
        // to scratch at VGPR_Count=84 and destroyed the pipeline).
        f32x4 win[NW];

        #pragma unroll
        for (int j = 0; j < 7 + PFD; ++j)
            asm volatile("global_load_dwordx4 %0, %1, off"
                         : "=v"(win[j]) : "v"(xbase + (size_t)j * DCH));

        #pragma unroll
        for (int i = 0; i < RPB; ++i) {
            // Issue this iteration's prefetch (row window-index i+7+PFD).
            if (i + 7 + PFD < NW)
                asm volatile("global_load_dwordx4 %0, %1, off"
                             : "=v"(win[i + 7 + PFD])
                             : "v"(xbase + (size_t)(i + 7 + PFD) * DCH));

            // Exact counted wait: loads+stores both count, in-order retire.
            // issued = loads_after_this_issue + i stores; required = window
            // loads 0..i+6 retired (stream position req).
            const int loads_iss = (i + 7 + PFD < NW) ? (8 + PFD + i) : NW;
            const int req = (i + 6 <= 6 + PFD) ? (i + 7) : (2 * (i + 6) - 6 - PFD);
            vmwait_sb(loads_iss + i - req);   // ramp 7..13, steady 14, drain 13..7

            const int r    = r0 + i;
            const bool nb  = (r >= e1b);
            const int offb = nb ? e1b : e0b;
            const int endb = nb ? e2b : e1b;
            const int t    = r - offb - 1;     // body position; -1 => cls
            const int Lb1  = endb - offb - 1;  // body length

            f32x4 o;
            if (t < 0) {
                o = win[i + 3];                // cls row: pass-through
            } else if (t >= 3 && t + 3 < Lb1) {
                float a0 = bias[0], a1 = bias[1], a2 = bias[2], a3 = bias[3];
                #pragma unroll
                for (int dt = 0; dt < 7; ++dt) {
                    const f32x4 v = win[i + dt];
                    a0 = fmaf(W[dt][0], v.x, a0);
                    a1 = fmaf(W[dt][1], v.y, a1);
                    a2 = fmaf(W[dt][2], v.z, a2);
                    a3 = fmaf(W[dt][3], v.w, a3);
                }
                o = (f32x4){a0, a1, a2, a3};
            } else {
                float a0 = bias[0], a1 = bias[1], a2 = bias[2], a3 = bias[3];
                #pragma unroll
                for (int dt = 0; dt < 7; ++dt) {
                    const int  tp    = t + dt - 3;
                    const bool valid = (tp >= 0) && (tp < Lb1);
                    const float mm   = valid ? 1.0f : 0.0f;
                    const f32x4 v = win[i + dt];
                    a0 = fmaf(mm * W[dt][0], v.x, a0);
                    a1 = fmaf(mm * W[dt][1], v.y, a1);
                    a2 = fmaf(mm * W[dt][2], v.z, a2);
                    a3 = fmaf(mm * W[dt][3], v.w, a3);
                }
                o = (f32x4){a0, a1, a2, a3};
            }

            // Store via asm so it stays at this stream position (the vmcnt
            // arithmetic above depends on store issue order).
            asm volatile("global_store_dwordx4 %0, %1, off"
                         :: "v"(obase + (size_t)i * DCH), "v"(o) : "memory");
        }
    } else {
        // Edge blocks (first/last tile only): simple bounds-checked path.
        for (int i = 0; i < RPB; ++i) {
            const int r = r0 + i;
            if (r >= n_rows) break;

            f32x4 wv[7];
            #pragma unroll
            for (int dt = 0; dt < 7; ++dt) {
                const int rr = r - 3 + dt;
                wv[dt] = (rr >= 0 && rr < n_rows)
                           ? *(const f32x4*)(x + (size_t)rr * DCH + c0)
                           : (f32x4){0.f, 0.f, 0.f, 0.f};
            }

            const bool nb  = (r >= e1b);
            const int offb = nb ? e1b : e0b;
            const int endb = nb ? e2b : e1b;
            const int t    = r - offb - 1;
            const int Lb1  = endb - offb - 1;

            f32x4 o;
            if (t < 0) {
                o = wv[3];
            } else {
                float a0 = bias[0], a1 = bias[1], a2 = bias[2], a3 = bias[3];
                #pragma unroll
                for (int dt = 0; dt < 7; ++dt) {
                    const int  tp    = t + dt - 3;
                    const bool valid = (tp >= 0) && (tp < Lb1);
                    const float mm   = valid ? 1.0f : 0.0f;
                    a0 = fmaf(mm * W[dt][0], wv[dt].x, a0);
                    a1 = fmaf(mm * W[dt][1], wv[dt].y, a1);
                    a2 = fmaf(mm * W[dt][2], wv[dt].z, a2);
                    a3 = fmaf(mm * W[dt][3], wv[dt].w, a3);
                }
                o = (f32x4){a0, a1, a2, a3};
            }
            *(f32x4*)(out + (size_t)r * DCH + c0) = o;
        }
    }
}

extern "C" void kernel_launch(void* const* d_in, const int* in_sizes, int n_in,
                              void* d_out, int out_size, void* d_ws, size_t ws_size,
                              hipStream_t stream) {
    const float* x       = (const float*)d_in[0];
    const float* w3      = (const float*)d_in[1];
    const float* b3      = (const float*)d_in[2];
    const float* w5      = (const float*)d_in[3];
    const float* b5      = (const float*)d_in[4];
    const float* w7      = (const float*)d_in[5];
    const float* b7      = (const float*)d_in[6];
    const int*   lengths = (const int*)d_in[7];

    const int n_bags = in_sizes[7];
    const int n_rows = in_sizes[0] / DCH;
    float* out = (float*)d_out;

    const int nblocks = (n_rows + RPB - 1) / RPB;
    ppeg_dwconv_kernel<<<nblocks, 128, 0, stream>>>(
        x, w3, b3, w5, b5, w7, b7, lengths, out, n_rows, n_bags, nblocks);
}

// Round 5
// 250.323 us; speedup vs baseline: 1.0472x; 1.0472x over previous
//
#include <hip/hip_runtime.h>

#define DCH 512     // channels
#define RPB 16      // rows per block
#define PD  6       // prefetch distance in rows
#define WN  (7 + PD)   // register ring: rows r-3 .. r+3+PD

typedef float f32x2 __attribute__((ext_vector_type(2)));

__global__ __launch_bounds__(256) void ppeg_dwconv_kernel(
    const float* __restrict__ x,
    const float* __restrict__ w3, const float* __restrict__ b3,
    const float* __restrict__ w5, const float* __restrict__ b5,
    const float* __restrict__ w7, const float* __restrict__ b7,
    const int* __restrict__ lengths,
    float* __restrict__ out, int n_rows, int n_bags, int nblocks)
{
    __shared__ int soff[40];   // prefix offsets, n_bags+1 entries

    const int tid = threadIdx.x;
    const int c0  = tid * 2;           // this thread's 2 channels (8B/lane)

    // XCD-aware bijective swizzle: consecutive tiles share an XCD's L2
    // (R1 evidence: FETCH_SIZE 87.6 -> 65.8 MB).
    int bid = blockIdx.x;
    {
        const int nx = 8;
        const int q  = nblocks / nx, rm = nblocks % nx;
        const int xcd = bid % nx, idx = bid / nx;
        bid = (xcd < rm ? xcd * (q + 1) : rm * (q + 1) + (xcd - rm) * q) + idx;
    }
    const int r0 = bid * RPB;
    if (r0 >= n_rows) return;

    if (tid == 0) {
        int acc = 0;
        for (int i = 0; i < n_bags; ++i) { soff[i] = acc; acc += lengths[i]; }
        soff[n_bags] = acc;
    }

    // Folded 7-tap weights: 2 ch/thread -> W is 14 VGPRs (was 28).
    // Footprint math (the R0-R4 lesson): W(14)+bias(2)+ring(26)+addr ~ 55,
    // under the 64-VGPR cliff -> 8 waves/SIMD WITH prefetch depth.
    float W[7][2], bias[2];
    #pragma unroll
    for (int q2 = 0; q2 < 2; ++q2) {
        const int d = c0 + q2;
        const float a0 = w7[d*7+0], a1 = w7[d*7+1], a2 = w7[d*7+2], a3 = w7[d*7+3],
                    a4 = w7[d*7+4], a5 = w7[d*7+5], a6 = w7[d*7+6];
        const float f0 = w5[d*5+0], f1 = w5[d*5+1], f2 = w5[d*5+2], f3 = w5[d*5+3], f4 = w5[d*5+4];
        const float e0 = w3[d*3+0], e1 = w3[d*3+1], e2 = w3[d*3+2];
        W[0][q2] = a0;
        W[1][q2] = a1 + f0;
        W[2][q2] = a2 + f1 + e0;
        W[3][q2] = a3 + f2 + e1 + 1.0f;
        W[4][q2] = a4 + f3 + e2;
        W[5][q2] = a5 + f4;
        W[6][q2] = a6;
        bias[q2] = b3[d] + b5[d] + b7[d];
    }

    __syncthreads();

    // Binary search for bag containing r0 (uniform, 5 LDS reads).
    int b = 0;
    #pragma unroll
    for (int s = 16; s >= 1; s >>= 1)
        if (b + s < n_bags && soff[b + s] <= r0) b += s;

    // A 16-row tile crosses at most one bag boundary (min bag = 2049 rows).
    const int e0b = soff[b];
    const int e1b = soff[b + 1];
    const int e2b = (b + 2 <= n_bags) ? soff[b + 2] : e1b;

    const bool interior = (r0 >= 3) && (r0 + RPB + 2 < n_rows);

    if (interior) {
        const float* xb = x + (size_t)(r0 - 3) * DCH + c0;
        float*       ob = out + (size_t)r0 * DCH + c0;

        // Register ring with PD rows of lookahead. Plain loads: the R0
        // structure compiled cleanly (no spill, per-iter scheduling);
        // asm pinning (R2-R4) is what created unallocatable live sets.
        f32x2 win[WN];
        #pragma unroll
        for (int j = 0; j < WN - 1; ++j)            // rows r0-3 .. r0+2+PD
            win[j] = *(const f32x2*)(xb + (size_t)j * DCH);

        #pragma unroll
        for (int i = 0; i < RPB; ++i) {
            // Ring invariant at iter i: win[j] = row r0-3+i+j.
            // Prefetch row r0+i+3+PD; stop once the tile's window
            // (max row r0+RPB+2) is fully issued.
            if (i + PD <= RPB - 1)
                win[WN - 1] = *(const f32x2*)(xb + (size_t)(i + WN - 1) * DCH);

            const int r    = r0 + i;
            const bool nb  = (r >= e1b);
            const int offb = nb ? e1b : e0b;
            const int endb = nb ? e2b : e1b;
            const int t    = r - offb - 1;     // body position; -1 => cls
            const int Lb1  = endb - offb - 1;  // body length

            f32x2 o;
            if (t < 0) {
                o = win[3];                    // cls row: pass-through
            } else if (t >= 3 && t + 3 < Lb1) {
                // Interior fast path: pure FMA chain, no masks.
                float a0 = bias[0], a1 = bias[1];
                #pragma unroll
                for (int dt = 0; dt < 7; ++dt) {
                    const f32x2 v = win[dt];
                    a0 = fmaf(W[dt][0], v.x, a0);
                    a1 = fmaf(W[dt][1], v.y, a1);
                }
                o = (f32x2){a0, a1};
            } else {
                // Bag-edge path (rare): masked taps reproduce zero padding.
                float a0 = bias[0], a1 = bias[1];
                #pragma unroll
                for (int dt = 0; dt < 7; ++dt) {
                    const int  tp    = t + dt - 3;
                    const bool valid = (tp >= 0) && (tp < Lb1);
                    const float mm   = valid ? 1.0f : 0.0f;
                    const f32x2 v = win[dt];
                    a0 = fmaf(mm * W[dt][0], v.x, a0);
                    a1 = fmaf(mm * W[dt][1], v.y, a1);
                }
                o = (f32x2){a0, a1};
            }

            // Output is write-once: nontemporal keeps L2 for input halos.
            __builtin_nontemporal_store(o, (f32x2*)(ob + (size_t)i * DCH));

            // Slide the ring (full unroll -> register renaming, no movs).
            #pragma unroll
            for (int j = 0; j < WN - 1; ++j) win[j] = win[j + 1];
        }
    } else {
        // Edge blocks (first/last tile only): simple bounds-checked path.
        for (int i = 0; i < RPB; ++i) {
            const int r = r0 + i;
            if (r >= n_rows) break;

            f32x2 wv[7];
            #pragma unroll
            for (int dt = 0; dt < 7; ++dt) {
                const int rr = r - 3 + dt;
                wv[dt] = (rr >= 0 && rr < n_rows)
                           ? *(const f32x2*)(x + (size_t)rr * DCH + c0)
                           : (f32x2){0.f, 0.f};
            }

            const bool nb  = (r >= e1b);
            const int offb = nb ? e1b : e0b;
            const int endb = nb ? e2b : e1b;
            const int t    = r - offb - 1;
            const int Lb1  = endb - offb - 1;

            f32x2 o;
            if (t < 0) {
                o = wv[3];
            } else {
                float a0 = bias[0], a1 = bias[1];
                #pragma unroll
                for (int dt = 0; dt < 7; ++dt) {
                    const int  tp    = t + dt - 3;
                    const bool valid = (tp >= 0) && (tp < Lb1);
                    const float mm   = valid ? 1.0f : 0.0f;
                    a0 = fmaf(mm * W[dt][0], wv[dt].x, a0);
                    a1 = fmaf(mm * W[dt][1], wv[dt].y, a1);
                }
                o = (f32x2){a0, a1};
            }
            *(f32x2*)(out + (size_t)r * DCH + c0) = o;
        }
    }
}

extern "C" void kernel_launch(void* const* d_in, const int* in_sizes, int n_in,
                              void* d_out, int out_size, void* d_ws, size_t ws_size,
                              hipStream_t stream) {
    const float* x       = (const float*)d_in[0];
    const float* w3      = (const float*)d_in[1];
    const float* b3      = (const float*)d_in[2];
    const float* w5      = (const float*)d_in[3];
    const float* b5      = (const float*)d_in[4];
    const float* w7      = (const float*)d_in[5];
    const float* b7      = (const float*)d_in[6];
    const int*   lengths = (const int*)d_in[7];

    const int n_bags = in_sizes[7];
    const int n_rows = in_sizes[0] / DCH;
    float* out = (float*)d_out;

    const int nblocks = (n_rows + RPB - 1) / RPB;
    ppeg_dwconv_kernel<<<nblocks, 256, 0, stream>>>(
        x, w3, b3, w5, b5, w7, b7, lengths, out, n_rows, n_bags, nblocks);
}